// Round 10
// baseline (48.847 us; speedup 1.0000x reference)
//
#include <hip/hip_runtime.h>
#include <math.h>

#pragma clang fp contract(off)

#define NUM_PRIORS 72192
#define BATCH      64
#define TOPK       200
#define CONF_TH    0.01f
#define NMS_TH     0.45f
#define NBINS      256
#define SLICES     32
#define ROWS       (NUM_PRIORS / SLICES)   // 2256
#define Q4         (ROWS / 2)              // 1128 float4 per slice
#define QB         (NUM_PRIORS / 2)        // 36096 float4 per batch
#define CAPS       64                      // candidate slots per slice segment
#define CAP        1024                    // max merged candidates per batch
#define KW         7                       // keep-mask words, ceil(200/32)
#define B255       0.99609375f             // 255/256: s >= B255 <=> bin_of(s) == 255

typedef unsigned long long u64;

// ---- binning: monotonic map score -> bin (cold path only) ----
__device__ __forceinline__ int bin_of(float s) {
    int b = (int)(s * 256.0f);
    return b > 255 ? 255 : b;
}

// ---- kernel 1: collect bin-255 candidates, store TRUE per-slice counts ----
__global__ __launch_bounds__(256) void collect255_kernel(const float* __restrict__ conf,
                                                         unsigned* __restrict__ scnt,
                                                         u64* __restrict__ cand) {
    __shared__ unsigned lcnt;
    const int b = blockIdx.y, slice = blockIdx.x, tid = threadIdx.x;
    if (tid == 0) lcnt = 0;
    __syncthreads();
    const float4* c4 = (const float4*)conf;
    const long base4 = (long)b * QB + (long)slice * Q4;
    const int prow0 = slice * ROWS;
    u64* seg = cand + ((long)b * SLICES + slice) * CAPS;

    float4 v0 = c4[base4 + tid];
    float4 v1 = c4[base4 + tid + 256];
    float4 v2 = c4[base4 + tid + 512];
    float4 v3 = c4[base4 + tid + 768];

#define P255(sv, pidx)                                                          \
    do {                                                                        \
        float s_ = (sv);                                                        \
        if (s_ >= B255) {                                                       \
            unsigned pos = atomicAdd(&lcnt, 1u);                                \
            if (pos < CAPS)                                                     \
                seg[pos] = ((u64)__float_as_uint(s_) << 32) |                   \
                           (u64)(0xFFFFFFFFu - (unsigned)(pidx));               \
        }                                                                       \
    } while (0)

    P255(v0.y, prow0 + 2 * tid);
    P255(v0.w, prow0 + 2 * tid + 1);
    P255(v1.y, prow0 + 2 * (tid + 256));
    P255(v1.w, prow0 + 2 * (tid + 256) + 1);
    P255(v2.y, prow0 + 2 * (tid + 512));
    P255(v2.w, prow0 + 2 * (tid + 512) + 1);
    P255(v3.y, prow0 + 2 * (tid + 768));
    P255(v3.w, prow0 + 2 * (tid + 768) + 1);
    if (tid < Q4 - 1024) {
        float4 vt = c4[base4 + tid + 1024];
        P255(vt.y, prow0 + 2 * (tid + 1024));
        P255(vt.w, prow0 + 2 * (tid + 1024) + 1);
    }
#undef P255
    __syncthreads();
    if (tid == 0) scnt[b * SLICES + slice] = lcnt;   // TRUE count (uncapped)
}

// ---- kernel 2: validity (+cold fallback), merge, rank, decode -> gbox/gsc/gkw ----
__global__ __launch_bounds__(256) void rankdecode_kernel(const float* __restrict__ loc,
                           const float* __restrict__ prior,
                           const float* __restrict__ conf,
                           const unsigned* __restrict__ scnt,
                           u64* __restrict__ cand,
                           float4* __restrict__ gbox,
                           float* __restrict__ gsc,
                           unsigned* __restrict__ gkw,
                           float* __restrict__ out) {
    __shared__ u64 keys[CAP];
    __shared__ int soff[SLICES + 1];
    __shared__ int scl[SLICES];
    __shared__ unsigned histc[NBINS];       // cold path only
    __shared__ unsigned lcnt32[SLICES];     // cold path only
    __shared__ int TshC, needfix;
    const int b = blockIdx.x, tid = threadIdx.x;

    // ---- phase A: wave0 scan + validity; others zero out/gkw ----
    if (tid < 64) {
        int s = tid;
        unsigned cs = (s < SLICES) ? scnt[b * SLICES + s] : 0u;
        int c = (cs < CAPS) ? (int)cs : CAPS;
        int v = c;
#pragma unroll
        for (int d = 1; d < 32; d <<= 1) {
            int o = __shfl_up(v, d);
            if ((int)tid >= d) v += o;
        }
        unsigned tot = cs;
#pragma unroll
        for (int d = 32; d >= 1; d >>= 1) tot += __shfl_xor(tot, d);
        u64 ovb = __ballot(cs > CAPS);
        if (s < SLICES) {
            int P = v - c;
            int off = P > CAP ? CAP : P;
            int rem = CAP - off;
            int cl = c < rem ? c : rem;
            soff[s] = off;
            scl[s] = cl;
            if (s == SLICES - 1) soff[SLICES] = (P + c > CAP) ? CAP : (P + c);
        }
        if (tid == 0) {
            needfix = (tot < TOPK) || (ovb != 0ull);
            TshC = 0;
        }
    }
    if (tid >= 64 && tid < 72) gkw[b * 8 + (tid - 64)] = 0u;
    {
        float* ob = out + (long)b * 2 * TOPK * 5;
        for (int i = tid; i < 2 * TOPK * 5; i += 256) ob[i] = 0.f;
    }
    __syncthreads();

    // ---- cold exact fallback (block-uniform; never taken on well-behaved data) ----
    if (needfix) {
        const float4* c4 = (const float4*)conf;
        for (int i = tid; i < NBINS; i += 256) histc[i] = 0u;
        __syncthreads();
        for (int q = tid; q < QB; q += 256) {
            float4 v = c4[(long)b * QB + q];
            if (v.y > CONF_TH) atomicAdd(&histc[bin_of(v.y)], 1u);
            if (v.w > CONF_TH) atomicAdd(&histc[bin_of(v.w)], 1u);
        }
        __syncthreads();
        for (int off = 1; off < NBINS; off <<= 1) {
            unsigned vv = 0u;
            if (tid < NBINS && tid + off < NBINS) vv = histc[tid + off];
            __syncthreads();
            if (tid < NBINS) histc[tid] += vv;
            __syncthreads();
        }
        if (tid < NBINS) {
            unsigned s0 = histc[tid];
            unsigned sn = (tid + 1 < NBINS) ? histc[tid + 1] : 0u;
            if (s0 >= TOPK && (tid == NBINS - 1 || sn < TOPK)) TshC = tid;
        }
        if (tid < SLICES) lcnt32[tid] = 0u;
        __syncthreads();
        const int T = TshC;
        for (int q = tid; q < QB; q += 256) {
            float4 v = c4[(long)b * QB + q];
            int sl = q / Q4;
            u64* seg = cand + ((long)b * SLICES + sl) * CAPS;
            if (v.y > CONF_TH && bin_of(v.y) >= T) {
                unsigned pos = atomicAdd(&lcnt32[sl], 1u);
                if (pos < CAPS)
                    seg[pos] = ((u64)__float_as_uint(v.y) << 32) |
                               (u64)(0xFFFFFFFFu - (unsigned)(2 * q));
            }
            if (v.w > CONF_TH && bin_of(v.w) >= T) {
                unsigned pos = atomicAdd(&lcnt32[sl], 1u);
                if (pos < CAPS)
                    seg[pos] = ((u64)__float_as_uint(v.w) << 32) |
                               (u64)(0xFFFFFFFFu - (unsigned)(2 * q + 1));
            }
        }
        __syncthreads();
        if (tid < 64) {
            int s = tid;
            unsigned cs = (s < SLICES) ? lcnt32[s] : 0u;
            int c = (cs < CAPS) ? (int)cs : CAPS;
            int v = c;
#pragma unroll
            for (int d = 1; d < 32; d <<= 1) {
                int o = __shfl_up(v, d);
                if ((int)tid >= d) v += o;
            }
            if (s < SLICES) {
                int P = v - c;
                int off = P > CAP ? CAP : P;
                int rem = CAP - off;
                int cl = c < rem ? c : rem;
                soff[s] = off;
                scl[s] = cl;
                if (s == SLICES - 1) soff[SLICES] = (P + c > CAP) ? CAP : (P + c);
            }
        }
        __syncthreads();
    }

    // ---- gather keys into LDS ----
    const int n = soff[SLICES];
    const int nn = (n + 15) & ~15;
    for (int pos = tid; pos < SLICES * CAPS; pos += 256) {
        int s = pos >> 6, idx = pos & 63;
        if (idx < scl[s])
            keys[soff[s] + idx] = cand[((long)b * SLICES + s) * CAPS + idx];
    }
    for (int i = n + tid; i < nn; i += 256) keys[i] = 0ull;   // zero pad
    __syncthreads();

    // ---- rank (exact top_k order: keys unique), 4 cands/thread, uniform guards ----
    const int smax = (n + 255) >> 8;              // block-uniform
    u64 kc0 = (tid < n) ? keys[tid] : 0ull;
    u64 kc1 = (tid + 256 < n) ? keys[tid + 256] : 0ull;
    u64 kc2 = (tid + 512 < n) ? keys[tid + 512] : 0ull;
    u64 kc3 = (tid + 768 < n) ? keys[tid + 768] : 0ull;
    int r0 = 0, r1 = 0, r2 = 0, r3 = 0;
    for (int k = 0; k < nn; k += 16) {
        u64 kb[16];
#pragma unroll
        for (int j = 0; j < 16; j++) kb[j] = keys[k + j];
        if (smax > 0) {
#pragma unroll
            for (int j = 0; j < 16; j++) r0 += (kb[j] > kc0) ? 1 : 0;
        }
        if (smax > 1) {
#pragma unroll
            for (int j = 0; j < 16; j++) r1 += (kb[j] > kc1) ? 1 : 0;
        }
        if (smax > 2) {
#pragma unroll
            for (int j = 0; j < 16; j++) r2 += (kb[j] > kc2) ? 1 : 0;
        }
        if (smax > 3) {
#pragma unroll
            for (int j = 0; j < 16; j++) r3 += (kb[j] > kc3) ? 1 : 0;
        }
    }
    // ---- fused decode of winners (identical float expressions to prior rounds) ----
#define DECODE(cidx, key, r)                                                    \
    do {                                                                        \
        if ((cidx) < n && (r) < TOPK) {                                         \
            float sc = __uint_as_float((unsigned)((key) >> 32));                \
            unsigned p = 0xFFFFFFFFu - (unsigned)((key) & 0xFFFFFFFFull);       \
            float4 l4 = ((const float4*)loc)[(long)b * NUM_PRIORS + p];         \
            float4 p4 = ((const float4*)prior)[p];                              \
            float cx = p4.x + (l4.x * 0.1f) * p4.z;                             \
            float cy = p4.y + (l4.y * 0.1f) * p4.w;                             \
            float w_ = p4.z * (float)exp((double)(l4.z * 0.2f));                \
            float h_ = p4.w * (float)exp((double)(l4.w * 0.2f));                \
            float x1 = cx - w_ * 0.5f, y1 = cy - h_ * 0.5f;                     \
            float x2 = cx + w_ * 0.5f, y2 = cy + h_ * 0.5f;                     \
            gbox[(long)b * TOPK + (r)] = make_float4(x1, y1, x2, y2);           \
            gsc[(long)b * TOPK + (r)] = sc;                                     \
            atomicOr(&gkw[b * 8 + ((r) >> 5)], 1u << ((r) & 31));               \
        }                                                                       \
    } while (0)
    DECODE(tid, kc0, r0);
    DECODE(tid + 256, kc1, r1);
    DECODE(tid + 512, kc2, r2);
    DECODE(tid + 768, kc3, r3);
#undef DECODE
}

// ---- kernel 3: IoU row-mask build + wave0 greedy (dead-group skip) + compact ----
__global__ __launch_bounds__(1024) void invrgreedy_kernel(const float4* __restrict__ gbox,
                           const float* __restrict__ gsc,
                           const unsigned* __restrict__ gkw,
                           float* __restrict__ out) {
    __shared__ float4 bbox[224];            // padded so batched loads never go OOB
    __shared__ float bsc_s[TOPK];
    __shared__ unsigned invR[TOPK][8];      // row i: ~suppression bits over j
    __shared__ unsigned kw0[8];
    __shared__ unsigned kwF[KW];            // final keep mask (published by wave 0)
    const int b = blockIdx.x, tid = threadIdx.x;

    if (tid < 224)
        bbox[tid] = (tid < TOPK) ? gbox[(long)b * TOPK + tid]
                                 : make_float4(0.f, 0.f, 0.f, 0.f);
    if (tid >= 256 && tid < 256 + TOPK) bsc_s[tid - 256] = gsc[(long)b * TOPK + (tid - 256)];
    if (tid >= 480 && tid < 488) kw0[tid - 480] = gkw[b * 8 + (tid - 480)];
    __syncthreads();

    // ---- build inverted row-major suppression mask, 4-way split + batched loads ----
    // thread 256*q + i owns row i, words {q, q+4} (q==3: word 3 only)
    {
        const int q = tid >> 8, i = tid & 255;
        if (i < TOPK) {
            const float4 ib = bbox[i];
            const float iar = (ib.z - ib.x) * (ib.w - ib.y);   // same expr as reference
#pragma unroll
            for (int wi = 0; wi < 2; wi++) {
                if (wi == 1 && q == 3) break;
                const int w = (wi == 0) ? q : q + 4;
                const int jbase = w * 32;
                unsigned inv = 0xFFFFFFFFu;
#pragma unroll
                for (int g = 0; g < 32; g += 8) {
                    float4 J[8];
#pragma unroll
                    for (int r = 0; r < 8; r++) J[r] = bbox[jbase + g + r];  // broadcast, batched
#pragma unroll
                    for (int r = 0; r < 8; r++) {
                        const int j = jbase + g + r;
                        if (j > i && j < TOPK) {
                            float4 jb = J[r];
                            float jar = (jb.z - jb.x) * (jb.w - jb.y);
                            float ltx = fmaxf(ib.x, jb.x);
                            float lty = fmaxf(ib.y, jb.y);
                            float rbx = fminf(ib.z, jb.z);
                            float rby = fminf(ib.w, jb.w);
                            float wx = fmaxf(rbx - ltx, 0.0f);
                            float wy = fmaxf(rby - lty, 0.0f);
                            float inter = wx * wy;
                            float uni = (iar + jar) - inter;
                            float iou = inter / fmaxf(uni, 1e-12f);
                            if (iou > NMS_TH) inv &= ~(1u << (g + r));
                        }
                    }
                }
                invR[i][w] = inv;
            }
        }
    }
    __syncthreads();

    // ---- greedy resolve: wave 0 only; dead-group skip (keep bits only clear) ----
    if (tid < 64) {
        unsigned kk[KW];
#pragma unroll
        for (int w = 0; w < KW; w++) kk[w] = kw0[w];
#pragma unroll
        for (int g = 0; g < TOPK; g += 8) {
            const unsigned live = (kk[g >> 5] >> (g & 31)) & 0xFFu;  // wave-uniform
            if (live == 0u) continue;               // dead forever -> skip 16 loads
            uint4 A[8], C[8];
#pragma unroll
            for (int r = 0; r < 8; r++) {
                A[r] = *(const uint4*)&invR[g + r][0];
                C[r] = *(const uint4*)&invR[g + r][4];
            }
#pragma unroll
            for (int r = 0; r < 8; r++) {
                const int i = g + r;                     // compile-time
                if ((kk[i >> 5] >> (i & 31)) & 1u) {
                    kk[0] &= A[r].x; kk[1] &= A[r].y; kk[2] &= A[r].z; kk[3] &= A[r].w;
                    kk[4] &= C[r].x; kk[5] &= C[r].y; kk[6] &= C[r].z;
                }
            }
        }
        if (tid == 0) {                                  // static indices (no scratch)
            kwF[0] = kk[0]; kwF[1] = kk[1]; kwF[2] = kk[2]; kwF[3] = kk[3];
            kwF[4] = kk[4]; kwF[5] = kk[5]; kwF[6] = kk[6];
        }
    }
    __syncthreads();

    // ---- compact + write kept rows (mask broadcast from LDS; out pre-zeroed) ----
    if (tid < TOPK) {
        const int wsel = tid >> 5, bsel = tid & 31;
        if ((kwF[wsel] >> bsel) & 1u) {
            int pos = 0;
#pragma unroll
            for (int w = 0; w < KW; w++) {
                unsigned kw_ = kwF[w];
                if (w < wsel) pos += __popc(kw_);
                else if (w == wsel) pos += __popc(kw_ & ((bsel == 0) ? 0u : (0xFFFFFFFFu >> (32 - bsel))));
            }
            float4 jb = bbox[tid];
            float* o = out + (((long)b * 2 + 1) * TOPK + pos) * 5;
            o[0] = bsc_s[tid];
            o[1] = jb.x;
            o[2] = jb.y;
            o[3] = jb.z;
            o[4] = jb.w;
        }
    }
}

extern "C" void kernel_launch(void* const* d_in, const int* in_sizes, int n_in,
                              void* d_out, int out_size, void* d_ws, size_t ws_size,
                              hipStream_t stream) {
    const float* loc   = (const float*)d_in[0];   // [64, 72192, 4]
    const float* conf  = (const float*)d_in[1];   // [64*72192, 2]
    const float* prior = (const float*)d_in[2];   // [72192, 4]
    float* out = (float*)d_out;                   // [64, 2, 200, 5]

    // ws layout (all regions fully written every launch -> no memset needed)
    char* w = (char*)d_ws;
    unsigned* scnt = (unsigned*)w;                         // 64*32 u32     = 8,192
    u64* cand      = (u64*)(w + 8192);                     // 64*32*64 u64  = 1,048,576
    float4* gbox   = (float4*)(w + 1056768);               // 64*200 f4     = 204,800
    float* gsc     = (float*)(w + 1261568);                // 64*200 f32    = 51,200
    unsigned* gkw  = (unsigned*)(w + 1312768);             // 64*8 u32      = 2,048

    collect255_kernel<<<dim3(SLICES, BATCH), 256, 0, stream>>>(conf, scnt, cand);
    rankdecode_kernel<<<BATCH, 256, 0, stream>>>(loc, prior, conf, scnt, cand,
                                                 gbox, gsc, gkw, out);
    invrgreedy_kernel<<<BATCH, 1024, 0, stream>>>(gbox, gsc, gkw, out);
}

// Round 11
// 39.105 us; speedup vs baseline: 1.2491x; 1.2491x over previous
//
#include <hip/hip_runtime.h>
#include <math.h>

#pragma clang fp contract(off)

#define NUM_PRIORS 72192
#define BATCH      64
#define TOPK       200
#define CONF_TH    0.01f
#define NMS_TH     0.45f
#define NBINS      256
#define SLICES     32
#define ROWS       (NUM_PRIORS / SLICES)   // 2256
#define Q4         (ROWS / 2)              // 1128 float4 per slice
#define QB         (NUM_PRIORS / 2)        // 36096 float4 per batch
#define CAPS       64                      // candidate slots per slice segment
#define CAP        1024                    // max merged candidates per batch
#define KW         7                       // keep-mask words, ceil(200/32)
#define NMS_NTH    1024                    // nms block size (16 waves = 4 waves/EU)
#define B255       0.99609375f             // 255/256: s >= B255 <=> bin_of(s) == 255

typedef unsigned long long u64;

// ---- binning: monotonic map score -> bin (cold path only) ----
__device__ __forceinline__ int bin_of(float s) {
    int b = (int)(s * 256.0f);
    return b > 255 ? 255 : b;
}

// ---- kernel 1: collect bin-255 candidates, store TRUE per-slice counts ----
__global__ __launch_bounds__(256) void collect255_kernel(const float* __restrict__ conf,
                                                         unsigned* __restrict__ scnt,
                                                         u64* __restrict__ cand) {
    __shared__ unsigned lcnt;
    const int b = blockIdx.y, slice = blockIdx.x, tid = threadIdx.x;
    if (tid == 0) lcnt = 0;
    __syncthreads();
    const float4* c4 = (const float4*)conf;
    const long base4 = (long)b * QB + (long)slice * Q4;
    const int prow0 = slice * ROWS;
    u64* seg = cand + ((long)b * SLICES + slice) * CAPS;

    float4 v0 = c4[base4 + tid];
    float4 v1 = c4[base4 + tid + 256];
    float4 v2 = c4[base4 + tid + 512];
    float4 v3 = c4[base4 + tid + 768];

#define P255(sv, pidx)                                                          \
    do {                                                                        \
        float s_ = (sv);                                                        \
        if (s_ >= B255) {                                                       \
            unsigned pos = atomicAdd(&lcnt, 1u);                                \
            if (pos < CAPS)                                                     \
                seg[pos] = ((u64)__float_as_uint(s_) << 32) |                   \
                           (u64)(0xFFFFFFFFu - (unsigned)(pidx));               \
        }                                                                       \
    } while (0)

    P255(v0.y, prow0 + 2 * tid);
    P255(v0.w, prow0 + 2 * tid + 1);
    P255(v1.y, prow0 + 2 * (tid + 256));
    P255(v1.w, prow0 + 2 * (tid + 256) + 1);
    P255(v2.y, prow0 + 2 * (tid + 512));
    P255(v2.w, prow0 + 2 * (tid + 512) + 1);
    P255(v3.y, prow0 + 2 * (tid + 768));
    P255(v3.w, prow0 + 2 * (tid + 768) + 1);
    if (tid < Q4 - 1024) {
        float4 vt = c4[base4 + tid + 1024];
        P255(vt.y, prow0 + 2 * (tid + 1024));
        P255(vt.w, prow0 + 2 * (tid + 1024) + 1);
    }
#undef P255
    __syncthreads();
    if (tid == 0) scnt[b * SLICES + slice] = lcnt;   // TRUE count (uncapped)
}

// ------- kernel 2: validity check (+exact cold fallback), merge, rank, decode,
//         row-mask NMS, wave0 greedy, compact -------
__global__ __launch_bounds__(NMS_NTH, 4) void nms_kernel(const float* __restrict__ loc,
                           const float* __restrict__ prior,
                           const float* __restrict__ conf,
                           const unsigned* __restrict__ scnt,
                           u64* __restrict__ cand,
                           float* __restrict__ out) {
    __shared__ u64 keys[CAP];
    __shared__ float4 bbox[224];            // padded so batched loads never go OOB
    __shared__ float bsc_s[TOPK];
    __shared__ unsigned invR[TOPK][8];      // row i: ~suppression bits over j (pad=~0)
    __shared__ unsigned kw0[8];
    __shared__ unsigned kwF[KW];            // final keep mask (published by wave 0)
    __shared__ int soff[SLICES + 1];
    __shared__ int scl[SLICES];
    __shared__ unsigned histc[NBINS];       // cold path only
    __shared__ unsigned lcnt32[SLICES];     // cold path only
    __shared__ int TshC, needfix;
    const int b = blockIdx.x, tid = threadIdx.x;

    // ---- phase A: wave0 scan + validity; others zero out/kw0 ----
    if (tid < 64) {
        int s = tid;
        unsigned cs = (s < SLICES) ? scnt[b * SLICES + s] : 0u;
        int c = (cs < CAPS) ? (int)cs : CAPS;
        int v = c;
#pragma unroll
        for (int d = 1; d < 32; d <<= 1) {
            int o = __shfl_up(v, d);
            if ((int)tid >= d) v += o;
        }
        unsigned tot = cs;
#pragma unroll
        for (int d = 32; d >= 1; d >>= 1) tot += __shfl_xor(tot, d);
        u64 ovb = __ballot(cs > CAPS);
        if (s < SLICES) {
            int P = v - c;
            int off = P > CAP ? CAP : P;
            int rem = CAP - off;
            int cl = c < rem ? c : rem;
            soff[s] = off;
            scl[s] = cl;
            if (s == SLICES - 1) soff[SLICES] = (P + c > CAP) ? CAP : (P + c);
        }
        if (tid == 0) {
            needfix = (tot < TOPK) || (ovb != 0ull);
            TshC = 0;
        }
    }
    {
        float* ob = out + (long)b * 2 * TOPK * 5;
        for (int i = tid; i < 2 * TOPK * 5; i += NMS_NTH) ob[i] = 0.f;
    }
    if (tid < 8) kw0[tid] = 0u;
    __syncthreads();

    // ---- cold exact fallback (block-uniform; never taken on well-behaved data) ----
    if (needfix) {
        const float4* c4 = (const float4*)conf;
        for (int i = tid; i < NBINS; i += NMS_NTH) histc[i] = 0u;
        __syncthreads();
        for (int q = tid; q < QB; q += NMS_NTH) {
            float4 v = c4[(long)b * QB + q];
            if (v.y > CONF_TH) atomicAdd(&histc[bin_of(v.y)], 1u);
            if (v.w > CONF_TH) atomicAdd(&histc[bin_of(v.w)], 1u);
        }
        __syncthreads();
        for (int off = 1; off < NBINS; off <<= 1) {
            unsigned vv = 0u;
            if (tid < NBINS && tid + off < NBINS) vv = histc[tid + off];
            __syncthreads();
            if (tid < NBINS) histc[tid] += vv;
            __syncthreads();
        }
        if (tid < NBINS) {
            unsigned s0 = histc[tid];
            unsigned sn = (tid + 1 < NBINS) ? histc[tid + 1] : 0u;
            if (s0 >= TOPK && (tid == NBINS - 1 || sn < TOPK)) TshC = tid;
        }
        if (tid < SLICES) lcnt32[tid] = 0u;
        __syncthreads();
        const int T = TshC;
        for (int q = tid; q < QB; q += NMS_NTH) {
            float4 v = c4[(long)b * QB + q];
            int sl = q / Q4;
            u64* seg = cand + ((long)b * SLICES + sl) * CAPS;
            if (v.y > CONF_TH && bin_of(v.y) >= T) {
                unsigned pos = atomicAdd(&lcnt32[sl], 1u);
                if (pos < CAPS)
                    seg[pos] = ((u64)__float_as_uint(v.y) << 32) |
                               (u64)(0xFFFFFFFFu - (unsigned)(2 * q));
            }
            if (v.w > CONF_TH && bin_of(v.w) >= T) {
                unsigned pos = atomicAdd(&lcnt32[sl], 1u);
                if (pos < CAPS)
                    seg[pos] = ((u64)__float_as_uint(v.w) << 32) |
                               (u64)(0xFFFFFFFFu - (unsigned)(2 * q + 1));
            }
        }
        __syncthreads();
        if (tid < 64) {
            int s = tid;
            unsigned cs = (s < SLICES) ? lcnt32[s] : 0u;
            int c = (cs < CAPS) ? (int)cs : CAPS;
            int v = c;
#pragma unroll
            for (int d = 1; d < 32; d <<= 1) {
                int o = __shfl_up(v, d);
                if ((int)tid >= d) v += o;
            }
            if (s < SLICES) {
                int P = v - c;
                int off = P > CAP ? CAP : P;
                int rem = CAP - off;
                int cl = c < rem ? c : rem;
                soff[s] = off;
                scl[s] = cl;
                if (s == SLICES - 1) soff[SLICES] = (P + c > CAP) ? CAP : (P + c);
            }
        }
        __syncthreads();
    }

    // ---- gather keys into LDS ----
    const int n = soff[SLICES];
    const int nn = (n + 15) & ~15;
    for (int pos = tid; pos < SLICES * CAPS; pos += NMS_NTH) {
        int s = pos >> 6, idx = pos & 63;
        if (idx < scl[s])
            keys[soff[s] + idx] = cand[((long)b * SLICES + s) * CAPS + idx];
    }
    for (int i = n + tid; i < nn; i += NMS_NTH) keys[i] = 0ull;   // zero pad
    __syncthreads();

    // ---- rank (exact top_k order: keys unique); only waves holding candidates run ----
    u64 kc = (tid < n) ? keys[tid] : 0ull;
    int rk = 0;
    if ((int)(tid & ~63u) < n) {                  // wave-uniform guard
        for (int k = 0; k < nn; k += 16) {
            u64 kb[16];
#pragma unroll
            for (int j = 0; j < 16; j++) kb[j] = keys[k + j];
#pragma unroll
            for (int j = 0; j < 16; j++) rk += (kb[j] > kc) ? 1 : 0;
        }
    }
    // ---- fused decode of winners (identical float expressions to prior rounds) ----
    if (tid < n && rk < TOPK) {
        u64 key = kc;
        float sc = __uint_as_float((unsigned)(key >> 32));
        unsigned p = 0xFFFFFFFFu - (unsigned)(key & 0xFFFFFFFFull);
        float4 l4 = ((const float4*)loc)[(long)b * NUM_PRIORS + p];
        float4 p4 = ((const float4*)prior)[p];
        float cx = p4.x + (l4.x * 0.1f) * p4.z;
        float cy = p4.y + (l4.y * 0.1f) * p4.w;
        float w_ = p4.z * (float)exp((double)(l4.z * 0.2f));
        float h_ = p4.w * (float)exp((double)(l4.w * 0.2f));
        float x1 = cx - w_ * 0.5f, y1 = cy - h_ * 0.5f;
        float x2 = cx + w_ * 0.5f, y2 = cy + h_ * 0.5f;
        bsc_s[rk] = sc;
        bbox[rk] = make_float4(x1, y1, x2, y2);
        atomicOr(&kw0[rk >> 5], 1u << (rk & 31));
    }
    __syncthreads();

    // ---- build inverted row-major suppression mask, 4-way split + batched loads ----
    // thread 256*q + i owns row i, words {q, q+4} (q==3: word 3 only)
    {
        const int q = tid >> 8, i = tid & 255;
        if (i < TOPK) {
            const float4 ib = bbox[i];
            const float iar = (ib.z - ib.x) * (ib.w - ib.y);   // same expr as reference
#pragma unroll
            for (int wi = 0; wi < 2; wi++) {
                if (wi == 1 && q == 3) break;
                const int w = (wi == 0) ? q : q + 4;
                const int jbase = w * 32;
                unsigned inv = 0xFFFFFFFFu;
#pragma unroll
                for (int g = 0; g < 32; g += 8) {
                    float4 J[8];
#pragma unroll
                    for (int r = 0; r < 8; r++) J[r] = bbox[jbase + g + r];  // broadcast, batched
#pragma unroll
                    for (int r = 0; r < 8; r++) {
                        const int j = jbase + g + r;
                        if (j > i && j < TOPK) {
                            float4 jb = J[r];
                            float jar = (jb.z - jb.x) * (jb.w - jb.y);
                            float ltx = fmaxf(ib.x, jb.x);
                            float lty = fmaxf(ib.y, jb.y);
                            float rbx = fminf(ib.z, jb.z);
                            float rby = fminf(ib.w, jb.w);
                            float wx = fmaxf(rbx - ltx, 0.0f);
                            float wy = fmaxf(rby - lty, 0.0f);
                            float inter = wx * wy;
                            float uni = (iar + jar) - inter;
                            float iou = inter / fmaxf(uni, 1e-12f);
                            if (iou > NMS_TH) inv &= ~(1u << (g + r));
                        }
                    }
                }
                invR[i][w] = inv;
            }
        }
    }
    __syncthreads();

    // ---- greedy resolve: wave 0 only; dead-group skip; 8 rows (16 b128) per group ----
    if (tid < 64) {
        unsigned kk[KW];
#pragma unroll
        for (int w = 0; w < KW; w++) kk[w] = kw0[w];
#pragma unroll
        for (int g = 0; g < TOPK; g += 8) {
            const unsigned live = (kk[g >> 5] >> (g & 31)) & 0xFFu;  // wave-uniform
            if (live == 0u) continue;               // dead forever -> skip 16 loads
            uint4 A[8], C[8];
#pragma unroll
            for (int r = 0; r < 8; r++) {
                A[r] = *(const uint4*)&invR[g + r][0];
                C[r] = *(const uint4*)&invR[g + r][4];
            }
#pragma unroll
            for (int r = 0; r < 8; r++) {
                const int i = g + r;                     // compile-time
                if ((kk[i >> 5] >> (i & 31)) & 1u) {
                    kk[0] &= A[r].x; kk[1] &= A[r].y; kk[2] &= A[r].z; kk[3] &= A[r].w;
                    kk[4] &= C[r].x; kk[5] &= C[r].y; kk[6] &= C[r].z;
                }
            }
        }
        if (tid == 0) {                                  // static indices (no scratch)
            kwF[0] = kk[0]; kwF[1] = kk[1]; kwF[2] = kk[2]; kwF[3] = kk[3];
            kwF[4] = kk[4]; kwF[5] = kk[5]; kwF[6] = kk[6];
        }
    }
    __syncthreads();

    // ---- compact + write kept rows (mask broadcast from LDS) ----
    if (tid < TOPK) {
        const int wsel = tid >> 5, bsel = tid & 31;
        if ((kwF[wsel] >> bsel) & 1u) {
            int pos = 0;
#pragma unroll
            for (int w = 0; w < KW; w++) {
                unsigned kw_ = kwF[w];
                if (w < wsel) pos += __popc(kw_);
                else if (w == wsel) pos += __popc(kw_ & ((bsel == 0) ? 0u : (0xFFFFFFFFu >> (32 - bsel))));
            }
            float4 jb = bbox[tid];
            float* o = out + (((long)b * 2 + 1) * TOPK + pos) * 5;
            o[0] = bsc_s[tid];
            o[1] = jb.x;
            o[2] = jb.y;
            o[3] = jb.z;
            o[4] = jb.w;
        }
    }
}

extern "C" void kernel_launch(void* const* d_in, const int* in_sizes, int n_in,
                              void* d_out, int out_size, void* d_ws, size_t ws_size,
                              hipStream_t stream) {
    const float* loc   = (const float*)d_in[0];   // [64, 72192, 4]
    const float* conf  = (const float*)d_in[1];   // [64*72192, 2]
    const float* prior = (const float*)d_in[2];   // [72192, 4]
    float* out = (float*)d_out;                   // [64, 2, 200, 5]

    // ws layout (all regions fully written every launch -> no memset needed)
    char* w = (char*)d_ws;
    unsigned* scnt = (unsigned*)w;                         // 64*32 u32    = 8,192
    u64* cand      = (u64*)(w + 8192);                     // 64*32*64 u64 = 1,048,576

    collect255_kernel<<<dim3(SLICES, BATCH), 256, 0, stream>>>(conf, scnt, cand);
    nms_kernel<<<BATCH, NMS_NTH, 0, stream>>>(loc, prior, conf, scnt, cand, out);
}

// Round 12
// 35.258 us; speedup vs baseline: 1.3854x; 1.1091x over previous
//
#include <hip/hip_runtime.h>
#include <math.h>

#pragma clang fp contract(off)

#define NUM_PRIORS 72192
#define BATCH      64
#define TOPK       200
#define CONF_TH    0.01f
#define NMS_TH     0.45f
#define NBINS      256
#define SLICES     32
#define ROWS       (NUM_PRIORS / SLICES)   // 2256
#define Q4         (ROWS / 2)              // 1128 float4 per slice
#define QB         (NUM_PRIORS / 2)        // 36096 float4 per batch
#define CAPS       64                      // candidate slots per slice segment
#define CAP        1024                    // max merged candidates per batch
#define KW         7                       // keep-mask words, ceil(200/32)
#define NMS_NTH    1024                    // nms block size (16 waves = 4 waves/EU)
#define B255       0.99609375f             // 255/256: s >= B255 <=> bin_of(s) == 255

typedef unsigned long long u64;

// ---- binning: monotonic map score -> bin (cold path only) ----
__device__ __forceinline__ int bin_of(float s) {
    int b = (int)(s * 256.0f);
    return b > 255 ? 255 : b;
}

// ---- kernel 1: collect bin-255 candidates, store TRUE per-slice counts ----
__global__ __launch_bounds__(256) void collect255_kernel(const float* __restrict__ conf,
                                                         unsigned* __restrict__ scnt,
                                                         u64* __restrict__ cand) {
    __shared__ unsigned lcnt;
    const int b = blockIdx.y, slice = blockIdx.x, tid = threadIdx.x;
    if (tid == 0) lcnt = 0;
    __syncthreads();
    const float4* c4 = (const float4*)conf;
    const long base4 = (long)b * QB + (long)slice * Q4;
    const int prow0 = slice * ROWS;
    u64* seg = cand + ((long)b * SLICES + slice) * CAPS;

    float4 v0 = c4[base4 + tid];
    float4 v1 = c4[base4 + tid + 256];
    float4 v2 = c4[base4 + tid + 512];
    float4 v3 = c4[base4 + tid + 768];

#define P255(sv, pidx)                                                          \
    do {                                                                        \
        float s_ = (sv);                                                        \
        if (s_ >= B255) {                                                       \
            unsigned pos = atomicAdd(&lcnt, 1u);                                \
            if (pos < CAPS)                                                     \
                seg[pos] = ((u64)__float_as_uint(s_) << 32) |                   \
                           (u64)(0xFFFFFFFFu - (unsigned)(pidx));               \
        }                                                                       \
    } while (0)

    P255(v0.y, prow0 + 2 * tid);
    P255(v0.w, prow0 + 2 * tid + 1);
    P255(v1.y, prow0 + 2 * (tid + 256));
    P255(v1.w, prow0 + 2 * (tid + 256) + 1);
    P255(v2.y, prow0 + 2 * (tid + 512));
    P255(v2.w, prow0 + 2 * (tid + 512) + 1);
    P255(v3.y, prow0 + 2 * (tid + 768));
    P255(v3.w, prow0 + 2 * (tid + 768) + 1);
    if (tid < Q4 - 1024) {
        float4 vt = c4[base4 + tid + 1024];
        P255(vt.y, prow0 + 2 * (tid + 1024));
        P255(vt.w, prow0 + 2 * (tid + 1024) + 1);
    }
#undef P255
    __syncthreads();
    if (tid == 0) scnt[b * SLICES + slice] = lcnt;   // TRUE count (uncapped)
}

// ------- kernel 2: validity check (+exact cold fallback), merge, rank, decode,
//         row-mask NMS (bracketed IoU), bit-skip greedy, compact -------
__global__ __launch_bounds__(NMS_NTH, 4) void nms_kernel(const float* __restrict__ loc,
                           const float* __restrict__ prior,
                           const float* __restrict__ conf,
                           const unsigned* __restrict__ scnt,
                           u64* __restrict__ cand,
                           float* __restrict__ out) {
    __shared__ alignas(16) u64 keys[CAP];
    __shared__ float4 bbox[224];            // padded so batched loads never go OOB
    __shared__ float bsc_s[TOPK];
    __shared__ alignas(16) unsigned invR[TOPK][8]; // row i: ~sup bits over j (pad=~0)
    __shared__ unsigned kw0[8];
    __shared__ unsigned kwF[KW];            // final keep mask (published by wave 0)
    __shared__ int soff[SLICES + 1];
    __shared__ int scl[SLICES];
    __shared__ unsigned histc[NBINS];       // cold path only
    __shared__ unsigned lcnt32[SLICES];     // cold path only
    __shared__ int TshC, needfix;
    const int b = blockIdx.x, tid = threadIdx.x;

    // ---- phase A: wave0 scan + validity; others zero out/kw0 ----
    if (tid < 64) {
        int s = tid;
        unsigned cs = (s < SLICES) ? scnt[b * SLICES + s] : 0u;
        int c = (cs < CAPS) ? (int)cs : CAPS;
        int v = c;
#pragma unroll
        for (int d = 1; d < 32; d <<= 1) {
            int o = __shfl_up(v, d);
            if ((int)tid >= d) v += o;
        }
        unsigned tot = cs;
#pragma unroll
        for (int d = 32; d >= 1; d >>= 1) tot += __shfl_xor(tot, d);
        u64 ovb = __ballot(cs > CAPS);
        if (s < SLICES) {
            int P = v - c;
            int off = P > CAP ? CAP : P;
            int rem = CAP - off;
            int cl = c < rem ? c : rem;
            soff[s] = off;
            scl[s] = cl;
            if (s == SLICES - 1) soff[SLICES] = (P + c > CAP) ? CAP : (P + c);
        }
        if (tid == 0) {
            needfix = (tot < TOPK) || (ovb != 0ull);
            TshC = 0;
        }
    }
    {
        float* ob = out + (long)b * 2 * TOPK * 5;
        for (int i = tid; i < 2 * TOPK * 5; i += NMS_NTH) ob[i] = 0.f;
    }
    if (tid < 8) kw0[tid] = 0u;
    __syncthreads();

    // ---- cold exact fallback (block-uniform; never taken on well-behaved data) ----
    if (needfix) {
        const float4* c4 = (const float4*)conf;
        for (int i = tid; i < NBINS; i += NMS_NTH) histc[i] = 0u;
        __syncthreads();
        for (int q = tid; q < QB; q += NMS_NTH) {
            float4 v = c4[(long)b * QB + q];
            if (v.y > CONF_TH) atomicAdd(&histc[bin_of(v.y)], 1u);
            if (v.w > CONF_TH) atomicAdd(&histc[bin_of(v.w)], 1u);
        }
        __syncthreads();
        for (int off = 1; off < NBINS; off <<= 1) {
            unsigned vv = 0u;
            if (tid < NBINS && tid + off < NBINS) vv = histc[tid + off];
            __syncthreads();
            if (tid < NBINS) histc[tid] += vv;
            __syncthreads();
        }
        if (tid < NBINS) {
            unsigned s0 = histc[tid];
            unsigned sn = (tid + 1 < NBINS) ? histc[tid + 1] : 0u;
            if (s0 >= TOPK && (tid == NBINS - 1 || sn < TOPK)) TshC = tid;
        }
        if (tid < SLICES) lcnt32[tid] = 0u;
        __syncthreads();
        const int T = TshC;
        for (int q = tid; q < QB; q += NMS_NTH) {
            float4 v = c4[(long)b * QB + q];
            int sl = q / Q4;
            u64* seg = cand + ((long)b * SLICES + sl) * CAPS;
            if (v.y > CONF_TH && bin_of(v.y) >= T) {
                unsigned pos = atomicAdd(&lcnt32[sl], 1u);
                if (pos < CAPS)
                    seg[pos] = ((u64)__float_as_uint(v.y) << 32) |
                               (u64)(0xFFFFFFFFu - (unsigned)(2 * q));
            }
            if (v.w > CONF_TH && bin_of(v.w) >= T) {
                unsigned pos = atomicAdd(&lcnt32[sl], 1u);
                if (pos < CAPS)
                    seg[pos] = ((u64)__float_as_uint(v.w) << 32) |
                               (u64)(0xFFFFFFFFu - (unsigned)(2 * q + 1));
            }
        }
        __syncthreads();
        if (tid < 64) {
            int s = tid;
            unsigned cs = (s < SLICES) ? lcnt32[s] : 0u;
            int c = (cs < CAPS) ? (int)cs : CAPS;
            int v = c;
#pragma unroll
            for (int d = 1; d < 32; d <<= 1) {
                int o = __shfl_up(v, d);
                if ((int)tid >= d) v += o;
            }
            if (s < SLICES) {
                int P = v - c;
                int off = P > CAP ? CAP : P;
                int rem = CAP - off;
                int cl = c < rem ? c : rem;
                soff[s] = off;
                scl[s] = cl;
                if (s == SLICES - 1) soff[SLICES] = (P + c > CAP) ? CAP : (P + c);
            }
        }
        __syncthreads();
    }

    // ---- gather keys into LDS ----
    const int n = soff[SLICES];
    const int nn = (n + 15) & ~15;
    for (int pos = tid; pos < SLICES * CAPS; pos += NMS_NTH) {
        int s = pos >> 6, idx = pos & 63;
        if (idx < scl[s])
            keys[soff[s] + idx] = cand[((long)b * SLICES + s) * CAPS + idx];
    }
    for (int i = n + tid; i < nn; i += NMS_NTH) keys[i] = 0ull;   // zero pad
    __syncthreads();

    // ---- rank (exact top_k order: keys unique); b128 loads; wave-uniform guard ----
    u64 kc = (tid < n) ? keys[tid] : 0ull;
    int rk = 0;
    if ((int)(tid & ~63u) < n) {
        const uint4* k4 = (const uint4*)keys;
        for (int k = 0; k < nn; k += 16) {
            uint4 q[8];
#pragma unroll
            for (int j = 0; j < 8; j++) q[j] = k4[(k >> 1) + j];
#pragma unroll
            for (int j = 0; j < 8; j++) {
                u64 a = ((u64)q[j].y << 32) | (u64)q[j].x;
                u64 c = ((u64)q[j].w << 32) | (u64)q[j].z;
                rk += (a > kc) ? 1 : 0;
                rk += (c > kc) ? 1 : 0;
            }
        }
    }
    // ---- fused decode of winners (identical float expressions to prior rounds) ----
    if (tid < n && rk < TOPK) {
        u64 key = kc;
        float sc = __uint_as_float((unsigned)(key >> 32));
        unsigned p = 0xFFFFFFFFu - (unsigned)(key & 0xFFFFFFFFull);
        float4 l4 = ((const float4*)loc)[(long)b * NUM_PRIORS + p];
        float4 p4 = ((const float4*)prior)[p];
        float cx = p4.x + (l4.x * 0.1f) * p4.z;
        float cy = p4.y + (l4.y * 0.1f) * p4.w;
        float w_ = p4.z * (float)exp((double)(l4.z * 0.2f));
        float h_ = p4.w * (float)exp((double)(l4.w * 0.2f));
        float x1 = cx - w_ * 0.5f, y1 = cy - h_ * 0.5f;
        float x2 = cx + w_ * 0.5f, y2 = cy + h_ * 0.5f;
        bsc_s[rk] = sc;
        bbox[rk] = make_float4(x1, y1, x2, y2);
        atomicOr(&kw0[rk >> 5], 1u << (rk & 31));
    }
    __syncthreads();

    // ---- build inverted row-major suppression mask, 4-way split + batched loads ----
    // bracketed IoU compare: exact divide only in the ~1e-6 ambiguous band (bit-exact)
    {
        const int q = tid >> 8, i = tid & 255;
        if (i < TOPK) {
            const float4 ib = bbox[i];
            const float iar = (ib.z - ib.x) * (ib.w - ib.y);   // same expr as reference
#pragma unroll
            for (int wi = 0; wi < 2; wi++) {
                if (wi == 1 && q == 3) break;
                const int w = (wi == 0) ? q : q + 4;
                const int jbase = w * 32;
                unsigned inv = 0xFFFFFFFFu;
#pragma unroll
                for (int g = 0; g < 32; g += 8) {
                    float4 J[8];
#pragma unroll
                    for (int r = 0; r < 8; r++) J[r] = bbox[jbase + g + r];  // broadcast, batched
#pragma unroll
                    for (int r = 0; r < 8; r++) {
                        const int j = jbase + g + r;
                        if (j > i && j < TOPK) {
                            float4 jb = J[r];
                            float jar = (jb.z - jb.x) * (jb.w - jb.y);
                            float ltx = fmaxf(ib.x, jb.x);
                            float lty = fmaxf(ib.y, jb.y);
                            float rbx = fminf(ib.z, jb.z);
                            float rby = fminf(ib.w, jb.w);
                            float wx = fmaxf(rbx - ltx, 0.0f);
                            float wy = fmaxf(rby - lty, 0.0f);
                            float inter = wx * wy;
                            float uni = fmaxf((iar + jar) - inter, 1e-12f);
                            float t045 = uni * NMS_TH;
                            bool sup = inter > t045 * 1.000001f;
                            bool amb = (inter >= t045 * 0.999999f) && !sup;
                            if (__builtin_expect(amb, 0)) {
                                // exact reference arithmetic for boundary cases
                                sup = (inter / uni) > NMS_TH;
                            }
                            if (sup) inv &= ~(1u << (g + r));
                        }
                    }
                }
                invR[i][w] = inv;
            }
        }
    }
    __syncthreads();

    // ---- greedy resolve: wave 0 only, bit-skip (visits only live rows ~keep count) ----
    if (tid < 64) {
        unsigned kk0 = kw0[0], kk1 = kw0[1], kk2 = kw0[2], kk3 = kw0[3];
        unsigned kk4 = kw0[4], kk5 = kw0[5], kk6 = kw0[6];
        const uint4* iv4 = (const uint4*)invR;
#define GSTEP(W, KKW)                                                           \
        {                                                                       \
            unsigned live = (KKW);                                              \
            while (live) {                                                      \
                int t = __ffs(live) - 1;                                        \
                int i = (W) * 32 + t;                                           \
                uint4 A = iv4[2 * i];                                           \
                uint4 C = iv4[2 * i + 1];                                       \
                kk0 &= A.x; kk1 &= A.y; kk2 &= A.z; kk3 &= A.w;                 \
                kk4 &= C.x; kk5 &= C.y; kk6 &= C.z;                             \
                unsigned above = ~((2u << t) - 1u);  /* t==31 -> 0 */           \
                live = (KKW) & above;                                           \
            }                                                                   \
        }
        GSTEP(0, kk0); GSTEP(1, kk1); GSTEP(2, kk2); GSTEP(3, kk3);
        GSTEP(4, kk4); GSTEP(5, kk5); GSTEP(6, kk6);
#undef GSTEP
        if (tid == 0) {
            kwF[0] = kk0; kwF[1] = kk1; kwF[2] = kk2; kwF[3] = kk3;
            kwF[4] = kk4; kwF[5] = kk5; kwF[6] = kk6;
        }
    }
    __syncthreads();

    // ---- compact + write kept rows (mask broadcast from LDS) ----
    if (tid < TOPK) {
        const int wsel = tid >> 5, bsel = tid & 31;
        if ((kwF[wsel] >> bsel) & 1u) {
            int pos = 0;
#pragma unroll
            for (int w = 0; w < KW; w++) {
                unsigned kw_ = kwF[w];
                if (w < wsel) pos += __popc(kw_);
                else if (w == wsel) pos += __popc(kw_ & ((bsel == 0) ? 0u : (0xFFFFFFFFu >> (32 - bsel))));
            }
            float4 jb = bbox[tid];
            float* o = out + (((long)b * 2 + 1) * TOPK + pos) * 5;
            o[0] = bsc_s[tid];
            o[1] = jb.x;
            o[2] = jb.y;
            o[3] = jb.z;
            o[4] = jb.w;
        }
    }
}

extern "C" void kernel_launch(void* const* d_in, const int* in_sizes, int n_in,
                              void* d_out, int out_size, void* d_ws, size_t ws_size,
                              hipStream_t stream) {
    const float* loc   = (const float*)d_in[0];   // [64, 72192, 4]
    const float* conf  = (const float*)d_in[1];   // [64*72192, 2]
    const float* prior = (const float*)d_in[2];   // [72192, 4]
    float* out = (float*)d_out;                   // [64, 2, 200, 5]

    // ws layout (all regions fully written every launch -> no memset needed)
    char* w = (char*)d_ws;
    unsigned* scnt = (unsigned*)w;                         // 64*32 u32    = 8,192
    u64* cand      = (u64*)(w + 8192);                     // 64*32*64 u64 = 1,048,576

    collect255_kernel<<<dim3(SLICES, BATCH), 256, 0, stream>>>(conf, scnt, cand);
    nms_kernel<<<BATCH, NMS_NTH, 0, stream>>>(loc, prior, conf, scnt, cand, out);
}